// Round 1
// baseline (109.694 us; speedup 1.0000x reference)
//
#include <hip/hip_runtime.h>
#include <math.h>

#define GSZ 32
#define NNODE (GSZ * GSZ * GSZ)
// ws layout (float units):
//   [0..3]      center.xyz, scale
//   [16 ..)     tris SoA: 9 components x F floats
//   [16384 ..)  phi: 32768 floats
//   [49152 ..)  flags: 32768 ints
#define WS_TRIS  16
#define WS_PHI   16384
#define WS_FLAGS 49152

__device__ __forceinline__ float sdivf(float n, float d) {
#pragma clang fp contract(off)
    float dd = (fabsf(d) < 1e-12f) ? 1e-12f : d;
    return n / dd;
}

// ---------- kernel 1: bbox of hull 1 -> center/scale; scale tris to SoA ----------
__global__ void k_setup(const float* __restrict__ verts, const int* __restrict__ faces,
                        float* __restrict__ ws, int V, int F) {
#pragma clang fp contract(off)
    const float* v1 = verts + (size_t)V * 3;  // hull 1 vertices
    float mn[3] = {1e30f, 1e30f, 1e30f};
    float mx[3] = {-1e30f, -1e30f, -1e30f};
    for (int i = threadIdx.x; i < V; i += blockDim.x) {
        for (int c = 0; c < 3; ++c) {
            float val = v1[i * 3 + c];
            mn[c] = fminf(mn[c], val);
            mx[c] = fmaxf(mx[c], val);
        }
    }
    for (int off = 32; off >= 1; off >>= 1) {
        for (int c = 0; c < 3; ++c) {
            mn[c] = fminf(mn[c], __shfl_down(mn[c], off));
            mx[c] = fmaxf(mx[c], __shfl_down(mx[c], off));
        }
    }
    __shared__ float smn[4][3], smx[4][3];
    __shared__ float s_c[3];
    __shared__ float s_s;
    int wave = threadIdx.x >> 6, lane = threadIdx.x & 63;
    if (lane == 0) {
        for (int c = 0; c < 3; ++c) { smn[wave][c] = mn[c]; smx[wave][c] = mx[c]; }
    }
    __syncthreads();
    if (threadIdx.x == 0) {
        float ext = -1e30f;
        for (int c = 0; c < 3; ++c) {
            float lo = fminf(fminf(smn[0][c], smn[1][c]), fminf(smn[2][c], smn[3][c]));
            float hi = fmaxf(fmaxf(smx[0][c], smx[1][c]), fmaxf(smx[2][c], smx[3][c]));
            s_c[c] = (lo + hi) * 0.5f;
            ext = fmaxf(ext, hi - lo);
        }
        s_s = (1.0f + 0.2f) * 0.5f * ext;
        ws[0] = s_c[0]; ws[1] = s_c[1]; ws[2] = s_c[2]; ws[3] = s_s;
    }
    __syncthreads();
    float cx = s_c[0], cy = s_c[1], cz = s_c[2], sc = s_s;
    float* tris = ws + WS_TRIS;
    for (int idx = threadIdx.x; idx < 3 * F; idx += blockDim.x) {
        int k = idx / F;
        int f = idx - k * F;
        int vi = faces[f * 3 + k];
        tris[(k * 3 + 0) * F + f] = (v1[vi * 3 + 0] - cx) / sc;
        tris[(k * 3 + 1) * F + f] = (v1[vi * 3 + 1] - cy) / sc;
        tris[(k * 3 + 2) * F + f] = (v1[vi * 3 + 2] - cz) / sc;
    }
}

// ---------- kernel 2: flag the grid nodes actually read by trilinear ----------
__global__ void k_mark(const float* __restrict__ verts, const float* __restrict__ ws,
                       int* __restrict__ flags, int V) {
#pragma clang fp contract(off)
    int t = blockIdx.x * blockDim.x + threadIdx.x;
    if (t >= V) return;
    float cx = ws[0], cy = ws[1], cz = ws[2], sc = ws[3];
    float px = (verts[t * 3 + 0] - cx) / sc;  // hull 0 vertices
    float py = (verts[t * 3 + 1] - cy) / sc;
    float pz = (verts[t * 3 + 2] - cz) / sc;
    float fx = (px + 1.0f) * 0.5f * 31.0f;
    float fy = (py + 1.0f) * 0.5f * 31.0f;
    float fz = (pz + 1.0f) * 0.5f * 31.0f;
    int x0 = (int)fmaxf(fminf(floorf(fx), 33.0f), -2.0f);
    int y0 = (int)fmaxf(fminf(floorf(fy), 33.0f), -2.0f);
    int z0 = (int)fmaxf(fminf(floorf(fz), 33.0f), -2.0f);
    for (int dz = 0; dz < 2; ++dz) {
        int zi = z0 + dz;
        if (zi < 0 || zi > 31) continue;
        for (int dy = 0; dy < 2; ++dy) {
            int yi = y0 + dy;
            if (yi < 0 || yi > 31) continue;
            for (int dx = 0; dx < 2; ++dx) {
                int xi = x0 + dx;
                if (xi < 0 || xi > 31) continue;
                flags[zi * 1024 + yi * 32 + xi] = 1;
            }
        }
    }
}

// ---------- kernel 3: phi at flagged nodes (one wave per node) ----------
__global__ void __launch_bounds__(256) k_phi(const float* __restrict__ tris,
                                             const int* __restrict__ flags,
                                             float* __restrict__ phi, int F) {
#pragma clang fp contract(off)
    int wave = threadIdx.x >> 6, lane = threadIdx.x & 63;
    int node = blockIdx.x * 4 + wave;
    if (!flags[node]) {
        if (lane == 0) phi[node] = 0.0f;
        return;
    }
    int x = node & 31, y = (node >> 5) & 31, z = node >> 10;
    float px = (float)((double)x * (2.0 / 31.0) - 1.0);
    float py = (float)((double)y * (2.0 / 31.0) - 1.0);
    float pz = (float)((double)z * (2.0 / 31.0) - 1.0);

    float mind2 = 1e30f;
    int hits = 0;
    for (int f = lane; f < F; f += 64) {
        float ax = tris[0 * F + f], ay = tris[1 * F + f], az = tris[2 * F + f];
        float bx = tris[3 * F + f], by = tris[4 * F + f], bz = tris[5 * F + f];
        float cx = tris[6 * F + f], cy = tris[7 * F + f], cz = tris[8 * F + f];

        float abx = bx - ax, aby = by - ay, abz = bz - az;
        float acx = cx - ax, acy = cy - ay, acz = cz - az;
        float apx = px - ax, apy = py - ay, apz = pz - az;
        float d1 = abx * apx + aby * apy + abz * apz;
        float d2 = acx * apx + acy * apy + acz * apz;
        float bpx = px - bx, bpy = py - by, bpz = pz - bz;
        float d3 = abx * bpx + aby * bpy + abz * bpz;
        float d4 = acx * bpx + acy * bpy + acz * bpz;
        float cpx = px - cx, cpy = py - cy, cpz = pz - cz;
        float d5 = abx * cpx + aby * cpy + abz * cpz;
        float d6 = acx * cpx + acy * cpy + acz * cpz;
        float vcb = d1 * d4 - d3 * d2;
        float vbb = d5 * d2 - d1 * d6;
        float vab = d3 * d6 - d5 * d4;
        float denom = vab + vbb + vcb;
        float v_in = sdivf(vbb, denom);
        float w_in = sdivf(vcb, denom);
        float rx = ax + abx * v_in + acx * w_in;
        float ry = ay + aby * v_in + acy * w_in;
        float rz = az + abz * v_in + acz * w_in;
        if (vab <= 0.0f && (d4 - d3) >= 0.0f && (d5 - d6) >= 0.0f) {
            float w = sdivf(d4 - d3, (d4 - d3) + (d5 - d6));
            rx = bx + (cx - bx) * w; ry = by + (cy - by) * w; rz = bz + (cz - bz) * w;
        }
        if (vbb <= 0.0f && d2 >= 0.0f && d6 <= 0.0f) {
            float w = sdivf(d2, d2 - d6);
            rx = ax + acx * w; ry = ay + acy * w; rz = az + acz * w;
        }
        if (vcb <= 0.0f && d1 >= 0.0f && d3 <= 0.0f) {
            float w = sdivf(d1, d1 - d3);
            rx = ax + abx * w; ry = ay + aby * w; rz = az + abz * w;
        }
        if (d6 >= 0.0f && d5 <= d6) { rx = cx; ry = cy; rz = cz; }
        if (d3 >= 0.0f && d4 <= d3) { rx = bx; ry = by; rz = bz; }
        if (d1 <= 0.0f && d2 <= 0.0f) { rx = ax; ry = ay; rz = az; }
        float ddx = px - rx, ddy = py - ry, ddz = pz - rz;
        float dd = ddx * ddx + ddy * ddy + ddz * ddz;
        mind2 = fminf(mind2, dd);

        // inside ray test (ray dir +x), e1 = ab, e2 = ac, s = ap
        float det = aby * (-acz) + abz * acy;
        float inv = sdivf(1.0f, det);
        float u = (apy * (-acz) + apz * acy) * inv;
        float qx = apy * abz - apz * aby;
        float qy = apz * abx - apx * abz;
        float qz = apx * aby - apy * abx;
        float v = qx * inv;
        float tt = (acx * qx + acy * qy + acz * qz) * inv;
        bool hit = (fabsf(det) > 1e-9f) && (u >= 0.0f) && (u <= 1.0f) &&
                   (v >= 0.0f) && ((u + v) <= 1.0f) && (tt > 0.0f);
        hits += hit ? 1 : 0;
    }
    for (int off = 32; off >= 1; off >>= 1) {
        mind2 = fminf(mind2, __shfl_xor(mind2, off));
        hits += __shfl_xor(hits, off);
    }
    if (lane == 0) phi[node] = (hits & 1) ? sqrtf(fmaxf(mind2, 0.0f)) : 0.0f;
}

// ---------- kernel 4: trilinear sample at hull-0 vertices + reduce ----------
__global__ void k_sum(const float* __restrict__ verts, const float* __restrict__ ws,
                      const float* __restrict__ phi, float* __restrict__ out, int V) {
#pragma clang fp contract(off)
    int t = threadIdx.x;
    float val = 0.0f;
    float cx = ws[0], cy = ws[1], cz = ws[2], sc = ws[3];
    for (int i = t; i < V; i += 1024) {
        float px = (verts[i * 3 + 0] - cx) / sc;
        float py = (verts[i * 3 + 1] - cy) / sc;
        float pz = (verts[i * 3 + 2] - cz) / sc;
        float fx = (px + 1.0f) * 0.5f * 31.0f;
        float fy = (py + 1.0f) * 0.5f * 31.0f;
        float fz = (pz + 1.0f) * 0.5f * 31.0f;
        float x0f = floorf(fx), y0f = floorf(fy), z0f = floorf(fz);
        float wx = fx - x0f, wy = fy - y0f, wz = fz - z0f;
        int x0 = (int)fmaxf(fminf(x0f, 33.0f), -2.0f);
        int y0 = (int)fmaxf(fminf(y0f, 33.0f), -2.0f);
        int z0 = (int)fmaxf(fminf(z0f, 33.0f), -2.0f);
        auto corner = [&](int zi, int yi, int xi, float w) -> float {
#pragma clang fp contract(off)
            bool valid = (zi >= 0) && (zi <= 31) && (yi >= 0) && (yi <= 31) &&
                         (xi >= 0) && (xi <= 31);
            int zc = min(max(zi, 0), 31);
            int yc = min(max(yi, 0), 31);
            int xc = min(max(xi, 0), 31);
            float vv = phi[zc * 1024 + yc * 32 + xc];
            return valid ? vv * w : 0.0f;
        };
        val += corner(z0, y0, x0, (1.0f - wz) * (1.0f - wy) * (1.0f - wx))
             + corner(z0, y0, x0 + 1, (1.0f - wz) * (1.0f - wy) * wx)
             + corner(z0, y0 + 1, x0, (1.0f - wz) * wy * (1.0f - wx))
             + corner(z0, y0 + 1, x0 + 1, (1.0f - wz) * wy * wx)
             + corner(z0 + 1, y0, x0, wz * (1.0f - wy) * (1.0f - wx))
             + corner(z0 + 1, y0, x0 + 1, wz * (1.0f - wy) * wx)
             + corner(z0 + 1, y0 + 1, x0, wz * wy * (1.0f - wx))
             + corner(z0 + 1, y0 + 1, x0 + 1, wz * wy * wx);
    }
    __shared__ float sm[1024];
    sm[t] = val;
    __syncthreads();
    for (int s = 512; s >= 1; s >>= 1) {
        if (t < s) sm[t] += sm[t + s];
        __syncthreads();
    }
    if (t == 0) out[0] = sm[0] * 0.25f;  // / H^2 with H=2
}

extern "C" void kernel_launch(void* const* d_in, const int* in_sizes, int n_in,
                              void* d_out, int out_size, void* d_ws, size_t ws_size,
                              hipStream_t stream) {
    const float* verts = (const float*)d_in[0];
    const int* faces = (const int*)d_in[1];
    float* out = (float*)d_out;
    float* ws = (float*)d_ws;

    int V = in_sizes[0] / 6;  // H=2 hulls x 3 comps
    int F = in_sizes[1] / 3;

    float* tris = ws + WS_TRIS;
    float* phi = ws + WS_PHI;
    int* flags = (int*)(ws + WS_FLAGS);

    k_setup<<<1, 256, 0, stream>>>(verts, faces, ws, V, F);
    hipMemsetAsync(flags, 0, NNODE * sizeof(int), stream);
    k_mark<<<(V + 255) / 256, 256, 0, stream>>>(verts, ws, flags, V);
    k_phi<<<NNODE / 4, 256, 0, stream>>>(tris, flags, phi, F);
    k_sum<<<1, 1024, 0, stream>>>(verts, ws, phi, out, V);
}

// Round 2
// 76.646 us; speedup vs baseline: 1.4312x; 1.4312x over previous
//
#include <hip/hip_runtime.h>
#include <math.h>

#define GSZ 32
#define NNODE (GSZ * GSZ * GSZ)

// fast guarded reciprocal (distance path only; branch boundaries are continuous)
__device__ __forceinline__ float rguard(float d) {
    float dd = (fabsf(d) < 1e-12f) ? 1e-12f : d;
    return __builtin_amdgcn_rcpf(dd);
}

// identical cell computation used by both the marking pass and k_sum
__device__ __forceinline__ void cell_of(float px, float py, float pz,
                                        int& x0, int& y0, int& z0,
                                        float& wx, float& wy, float& wz) {
#pragma clang fp contract(off)
    float fx = (px + 1.0f) * 0.5f * 31.0f;
    float fy = (py + 1.0f) * 0.5f * 31.0f;
    float fz = (pz + 1.0f) * 0.5f * 31.0f;
    float x0f = floorf(fx), y0f = floorf(fy), z0f = floorf(fz);
    wx = fx - x0f; wy = fy - y0f; wz = fz - z0f;
    x0 = (int)fmaxf(fminf(x0f, 33.0f), -2.0f);
    y0 = (int)fmaxf(fminf(y0f, 33.0f), -2.0f);
    z0 = (int)fmaxf(fminf(z0f, 33.0f), -2.0f);
}

// ---- setup: bbox hull1 -> params; triangle records (AoS 12f); mark+compact nodes ----
__global__ void k_setup(const float* __restrict__ verts, const int* __restrict__ faces,
                        float* __restrict__ par, float* __restrict__ tri,
                        int* __restrict__ flags, int* __restrict__ cnt,
                        int* __restrict__ list, int V, int F) {
#pragma clang fp contract(off)
    const float* v1 = verts + (size_t)V * 3;  // hull 1
    float mn[3] = {1e30f, 1e30f, 1e30f};
    float mx[3] = {-1e30f, -1e30f, -1e30f};
    for (int i = threadIdx.x; i < V; i += blockDim.x) {
        for (int c = 0; c < 3; ++c) {
            float val = v1[i * 3 + c];
            mn[c] = fminf(mn[c], val);
            mx[c] = fmaxf(mx[c], val);
        }
    }
    for (int off = 32; off >= 1; off >>= 1) {
        for (int c = 0; c < 3; ++c) {
            mn[c] = fminf(mn[c], __shfl_down(mn[c], off));
            mx[c] = fmaxf(mx[c], __shfl_down(mx[c], off));
        }
    }
    __shared__ float smn[4][3], smx[4][3];
    __shared__ float s_c[3];
    __shared__ float s_s;
    int wave = threadIdx.x >> 6, lane = threadIdx.x & 63;
    if (lane == 0)
        for (int c = 0; c < 3; ++c) { smn[wave][c] = mn[c]; smx[wave][c] = mx[c]; }
    __syncthreads();
    if (threadIdx.x == 0) {
        float ext = -1e30f;
        for (int c = 0; c < 3; ++c) {
            float lo = fminf(fminf(smn[0][c], smn[1][c]), fminf(smn[2][c], smn[3][c]));
            float hi = fmaxf(fmaxf(smx[0][c], smx[1][c]), fmaxf(smx[2][c], smx[3][c]));
            s_c[c] = (lo + hi) * 0.5f;
            ext = fmaxf(ext, hi - lo);
        }
        s_s = (1.0f + 0.2f) * 0.5f * ext;
        par[0] = s_c[0]; par[1] = s_c[1]; par[2] = s_c[2]; par[3] = s_s;
    }
    __syncthreads();
    float cx0 = s_c[0], cy0 = s_c[1], cz0 = s_c[2], sc = s_s;

    // triangle records: a(3) b(3) c(3) inv_det det pad   (inv_det exact IEEE)
    for (int f = threadIdx.x; f < F; f += blockDim.x) {
        int i0 = faces[f * 3 + 0], i1 = faces[f * 3 + 1], i2 = faces[f * 3 + 2];
        float ax = (v1[i0 * 3 + 0] - cx0) / sc, ay = (v1[i0 * 3 + 1] - cy0) / sc,
              az = (v1[i0 * 3 + 2] - cz0) / sc;
        float bx = (v1[i1 * 3 + 0] - cx0) / sc, by = (v1[i1 * 3 + 1] - cy0) / sc,
              bz = (v1[i1 * 3 + 2] - cz0) / sc;
        float cx = (v1[i2 * 3 + 0] - cx0) / sc, cy = (v1[i2 * 3 + 1] - cy0) / sc,
              cz = (v1[i2 * 3 + 2] - cz0) / sc;
        float aby = by - ay, abz = bz - az;
        float acy = cy - ay, acz = cz - az;
        float det = aby * (-acz) + abz * acy;
        float dd = (fabsf(det) < 1e-12f) ? 1e-12f : det;
        float inv = 1.0f / dd;  // IEEE — parity test must stay bit-exact
        float* r = tri + (size_t)f * 12;
        r[0] = ax; r[1] = ay; r[2] = az;
        r[3] = bx; r[4] = by; r[5] = bz;
        r[6] = cx; r[7] = cy; r[8] = cz;
        r[9] = inv; r[10] = det; r[11] = 0.0f;
    }

    // mark + compact the grid nodes actually read by trilinear (hull-0 points)
    for (int i = threadIdx.x; i < V; i += blockDim.x) {
        float px = (verts[i * 3 + 0] - cx0) / sc;
        float py = (verts[i * 3 + 1] - cy0) / sc;
        float pz = (verts[i * 3 + 2] - cz0) / sc;
        int x0, y0, z0; float wx, wy, wz;
        cell_of(px, py, pz, x0, y0, z0, wx, wy, wz);
        for (int dz = 0; dz < 2; ++dz) {
            int zi = z0 + dz;
            if (zi < 0 || zi > 31) continue;
            for (int dy = 0; dy < 2; ++dy) {
                int yi = y0 + dy;
                if (yi < 0 || yi > 31) continue;
                for (int dx = 0; dx < 2; ++dx) {
                    int xi = x0 + dx;
                    if (xi < 0 || xi > 31) continue;
                    int node = zi * 1024 + yi * 32 + xi;
                    if (atomicExch(&flags[node], 1) == 0) {
                        int p = atomicAdd(cnt, 1);
                        list[p] = node;
                    }
                }
            }
        }
    }
}

// ---- main: one wave per (active node, 64-triangle chunk), persistent grid ----
__global__ void __launch_bounds__(256) k_main(const float* __restrict__ tri,
                                              const int* __restrict__ list,
                                              const int* __restrict__ cnt,
                                              unsigned int* __restrict__ d2b,
                                              int* __restrict__ hits,
                                              int F, int nch,
                                              unsigned long long magic) {
    const int wave = threadIdx.x >> 6, lane = threadIdx.x & 63;
    const int wid = blockIdx.x * 4 + wave;
    const int nw = gridDim.x * 4;
    const int n = cnt[0];
    const int total = n * nch;
    for (int w = wid; w < total; w += nw) {
        const int q = (int)(((unsigned long long)(unsigned int)w * magic) >> 40);
        const int ck = w - q * nch;
        const int node = list[q];
        const int xi = node & 31, yi = (node >> 5) & 31, zi = node >> 10;
        float px, py, pz;
        {
#pragma clang fp contract(off)
            px = (float)((double)xi * (2.0 / 31.0) - 1.0);
            py = (float)((double)yi * (2.0 / 31.0) - 1.0);
            pz = (float)((double)zi * (2.0 / 31.0) - 1.0);
        }
        float mind2 = 1e30f;
        int h = 0;
        const int f = ck * 64 + lane;
        if (f < F) {
            const float* r = tri + (size_t)f * 12;
            float ax = r[0], ay = r[1], az = r[2];
            float bx = r[3], by = r[4], bz = r[5];
            float cx = r[6], cy = r[7], cz = r[8];
            float inv = r[9], det = r[10];
            float abx = bx - ax, aby = by - ay, abz = bz - az;
            float acx = cx - ax, acy = cy - ay, acz = cz - az;
            float apx = px - ax, apy = py - ay, apz = pz - az;
            // ---- distance path: contraction + fast rcp (continuous at all branch bounds)
            {
#pragma clang fp contract(fast)
                float d1 = abx * apx + aby * apy + abz * apz;
                float d2 = acx * apx + acy * apy + acz * apz;
                float bpx = px - bx, bpy = py - by, bpz = pz - bz;
                float d3 = abx * bpx + aby * bpy + abz * bpz;
                float d4 = acx * bpx + acy * bpy + acz * bpz;
                float cpx = px - cx, cpy = py - cy, cpz = pz - cz;
                float d5 = abx * cpx + aby * cpy + abz * cpz;
                float d6 = acx * cpx + acy * cpy + acz * cpz;
                float vc = d1 * d4 - d3 * d2;
                float vb = d5 * d2 - d1 * d6;
                float va = d3 * d6 - d5 * d4;
                float denom = va + vb + vc;
                float rd = rguard(denom);
                float v_in = vb * rd, w_in = vc * rd;
                float rx = ax + abx * v_in + acx * w_in;
                float ry = ay + aby * v_in + acy * w_in;
                float rz = az + abz * v_in + acz * w_in;
                if (va <= 0.0f && (d4 - d3) >= 0.0f && (d5 - d6) >= 0.0f) {
                    float w = (d4 - d3) * rguard((d4 - d3) + (d5 - d6));
                    rx = bx + (cx - bx) * w; ry = by + (cy - by) * w; rz = bz + (cz - bz) * w;
                }
                if (vb <= 0.0f && d2 >= 0.0f && d6 <= 0.0f) {
                    float w = d2 * rguard(d2 - d6);
                    rx = ax + acx * w; ry = ay + acy * w; rz = az + acz * w;
                }
                if (vc <= 0.0f && d1 >= 0.0f && d3 <= 0.0f) {
                    float w = d1 * rguard(d1 - d3);
                    rx = ax + abx * w; ry = ay + aby * w; rz = az + abz * w;
                }
                if (d6 >= 0.0f && d5 <= d6) { rx = cx; ry = cy; rz = cz; }
                if (d3 >= 0.0f && d4 <= d3) { rx = bx; ry = by; rz = bz; }
                if (d1 <= 0.0f && d2 <= 0.0f) { rx = ax; ry = ay; rz = az; }
                float ddx = px - rx, ddy = py - ry, ddz = pz - rz;
                mind2 = ddx * ddx + ddy * ddy + ddz * ddz;
            }
            // ---- parity path: bit-exact (discontinuous: a flip costs ~0.1 on the loss)
            {
#pragma clang fp contract(off)
                float u = (apy * (-acz) + apz * acy) * inv;
                float qx = apy * abz - apz * aby;
                float qy = apz * abx - apx * abz;
                float qz = apx * aby - apy * abx;
                float v = qx * inv;
                float tt = (acx * qx + acy * qy + acz * qz) * inv;
                h = (fabsf(det) > 1e-9f && u >= 0.0f && u <= 1.0f && v >= 0.0f &&
                     (u + v) <= 1.0f && tt > 0.0f) ? 1 : 0;
            }
        }
        for (int off = 32; off >= 1; off >>= 1) {
            mind2 = fminf(mind2, __shfl_xor(mind2, off));
            h += __shfl_xor(h, off);
        }
        if (lane == 0) {
            atomicMin(d2b + node, __float_as_uint(mind2));
            atomicAdd(hits + node, h);
        }
    }
}

// ---- trilinear sample at hull-0 vertices + reduce; phi built on the fly ----
__global__ void k_sum(const float* __restrict__ verts, const float* __restrict__ par,
                      const unsigned int* __restrict__ d2b, const int* __restrict__ hits,
                      float* __restrict__ out, int V) {
#pragma clang fp contract(off)
    int t = threadIdx.x;
    float val = 0.0f;
    float cx = par[0], cy = par[1], cz = par[2], sc = par[3];
    for (int i = t; i < V; i += 1024) {
        float px = (verts[i * 3 + 0] - cx) / sc;
        float py = (verts[i * 3 + 1] - cy) / sc;
        float pz = (verts[i * 3 + 2] - cz) / sc;
        int x0, y0, z0; float wx, wy, wz;
        cell_of(px, py, pz, x0, y0, z0, wx, wy, wz);
        auto corner = [&](int zi, int yi, int xi, float w) -> float {
#pragma clang fp contract(off)
            bool valid = (zi >= 0) && (zi <= 31) && (yi >= 0) && (yi <= 31) &&
                         (xi >= 0) && (xi <= 31);
            int zc = min(max(zi, 0), 31);
            int yc = min(max(yi, 0), 31);
            int xc = min(max(xi, 0), 31);
            int idx = zc * 1024 + yc * 32 + xc;
            float vv = (hits[idx] & 1) ? sqrtf(fmaxf(__uint_as_float(d2b[idx]), 0.0f))
                                       : 0.0f;
            return valid ? vv * w : 0.0f;
        };
        val += corner(z0, y0, x0, (1.0f - wz) * (1.0f - wy) * (1.0f - wx))
             + corner(z0, y0, x0 + 1, (1.0f - wz) * (1.0f - wy) * wx)
             + corner(z0, y0 + 1, x0, (1.0f - wz) * wy * (1.0f - wx))
             + corner(z0, y0 + 1, x0 + 1, (1.0f - wz) * wy * wx)
             + corner(z0 + 1, y0, x0, wz * (1.0f - wy) * (1.0f - wx))
             + corner(z0 + 1, y0, x0 + 1, wz * (1.0f - wy) * wx)
             + corner(z0 + 1, y0 + 1, x0, wz * wy * (1.0f - wx))
             + corner(z0 + 1, y0 + 1, x0 + 1, wz * wy * wx);
    }
    __shared__ float sm[1024];
    sm[t] = val;
    __syncthreads();
    for (int s = 512; s >= 1; s >>= 1) {
        if (t < s) sm[t] += sm[t + s];
        __syncthreads();
    }
    if (t == 0) out[0] = sm[0] * 0.25f;  // / H^2, H=2
}

extern "C" void kernel_launch(void* const* d_in, const int* in_sizes, int n_in,
                              void* d_out, int out_size, void* d_ws, size_t ws_size,
                              hipStream_t stream) {
    const float* verts = (const float*)d_in[0];
    const int* faces = (const int*)d_in[1];
    float* out = (float*)d_out;
    float* ws = (float*)d_ws;

    int V = in_sizes[0] / 6;  // 2 hulls x 3 comps
    int F = in_sizes[1] / 3;

    float* par = ws;                                   // 4 floats
    float* tri = ws + 16;                              // 12*F floats
    unsigned int* d2b = (unsigned int*)(tri + 12 * (size_t)F);
    int* hits = (int*)(d2b + NNODE);
    int* flags = hits + NNODE;
    int* cnt = flags + NNODE;
    int* list = cnt + 1;                               // up to 8*V entries

    int nch = (F + 63) / 64;
    unsigned long long magic = ((1ULL << 40) + (unsigned long long)nch - 1) / (unsigned long long)nch;

    hipMemsetAsync(d2b, 0xFF, NNODE * sizeof(unsigned int), stream);      // +inf as uint
    hipMemsetAsync(hits, 0, (2 * NNODE + 1) * sizeof(int), stream);       // hits, flags, cnt
    k_setup<<<1, 256, 0, stream>>>(verts, faces, par, tri, flags, cnt, list, V, F);
    k_main<<<2048, 256, 0, stream>>>(tri, list, cnt, d2b, hits, F, nch, magic);
    k_sum<<<1, 1024, 0, stream>>>(verts, par, d2b, hits, out, V);
}

// Round 3
// 72.627 us; speedup vs baseline: 1.5104x; 1.0553x over previous
//
#include <hip/hip_runtime.h>
#include <math.h>

#define GSZ 32
#define NNODE (GSZ * GSZ * GSZ)

// fast guarded reciprocal (distance path only; branch boundaries are continuous)
__device__ __forceinline__ float rguard(float d) {
    float dd = (fabsf(d) < 1e-12f) ? 1e-12f : d;
    return __builtin_amdgcn_rcpf(dd);
}

// identical cell computation used by both the marking pass and k_sum
__device__ __forceinline__ void cell_of(float px, float py, float pz,
                                        int& x0, int& y0, int& z0,
                                        float& wx, float& wy, float& wz) {
#pragma clang fp contract(off)
    float fx = (px + 1.0f) * 0.5f * 31.0f;
    float fy = (py + 1.0f) * 0.5f * 31.0f;
    float fz = (pz + 1.0f) * 0.5f * 31.0f;
    float x0f = floorf(fx), y0f = floorf(fy), z0f = floorf(fz);
    wx = fx - x0f; wy = fy - y0f; wz = fz - z0f;
    x0 = (int)fmaxf(fminf(x0f, 33.0f), -2.0f);
    y0 = (int)fmaxf(fminf(y0f, 33.0f), -2.0f);
    z0 = (int)fmaxf(fminf(z0f, 33.0f), -2.0f);
}

// ---- init: d2b=+inf(bits 0xFFFFFFFF), hits=0, flags=0, cnt=0 (replaces memsets) ----
__global__ void k_init(uint4* __restrict__ d2b4, uint4* __restrict__ hf4,
                       int* __restrict__ cnt) {
    int t = blockIdx.x * blockDim.x + threadIdx.x;   // 64*256 = 16384 threads
    if (t < NNODE / 4)
        d2b4[t] = make_uint4(0xFFFFFFFFu, 0xFFFFFFFFu, 0xFFFFFFFFu, 0xFFFFFFFFu);
    hf4[t] = make_uint4(0u, 0u, 0u, 0u);             // hits + flags, 2*NNODE ints
    if (t == 0) cnt[0] = 0;
}

// ---- setup: bbox hull1 -> params; triangle records (AoS 12f); mark+compact nodes ----
__global__ void k_setup(const float* __restrict__ verts, const int* __restrict__ faces,
                        float* __restrict__ par, float* __restrict__ tri,
                        int* __restrict__ flags, int* __restrict__ cnt,
                        int* __restrict__ list, int V, int F) {
#pragma clang fp contract(off)
    const float* v1 = verts + (size_t)V * 3;  // hull 1
    float mn[3] = {1e30f, 1e30f, 1e30f};
    float mx[3] = {-1e30f, -1e30f, -1e30f};
    for (int i = threadIdx.x; i < V; i += blockDim.x) {
        for (int c = 0; c < 3; ++c) {
            float val = v1[i * 3 + c];
            mn[c] = fminf(mn[c], val);
            mx[c] = fmaxf(mx[c], val);
        }
    }
    for (int off = 32; off >= 1; off >>= 1) {
        for (int c = 0; c < 3; ++c) {
            mn[c] = fminf(mn[c], __shfl_down(mn[c], off));
            mx[c] = fmaxf(mx[c], __shfl_down(mx[c], off));
        }
    }
    __shared__ float smn[4][3], smx[4][3];
    __shared__ float s_c[3];
    __shared__ float s_s;
    int wave = threadIdx.x >> 6, lane = threadIdx.x & 63;
    if (lane == 0)
        for (int c = 0; c < 3; ++c) { smn[wave][c] = mn[c]; smx[wave][c] = mx[c]; }
    __syncthreads();
    if (threadIdx.x == 0) {
        float ext = -1e30f;
        for (int c = 0; c < 3; ++c) {
            float lo = fminf(fminf(smn[0][c], smn[1][c]), fminf(smn[2][c], smn[3][c]));
            float hi = fmaxf(fmaxf(smx[0][c], smx[1][c]), fmaxf(smx[2][c], smx[3][c]));
            s_c[c] = (lo + hi) * 0.5f;
            ext = fmaxf(ext, hi - lo);
        }
        s_s = (1.0f + 0.2f) * 0.5f * ext;
        par[0] = s_c[0]; par[1] = s_c[1]; par[2] = s_c[2]; par[3] = s_s;
    }
    __syncthreads();
    float cx0 = s_c[0], cy0 = s_c[1], cz0 = s_c[2], sc = s_s;

    // triangle records: a(3) b(3) c(3) inv_det det pad   (inv_det exact IEEE)
    for (int f = threadIdx.x; f < F; f += blockDim.x) {
        int i0 = faces[f * 3 + 0], i1 = faces[f * 3 + 1], i2 = faces[f * 3 + 2];
        float ax = (v1[i0 * 3 + 0] - cx0) / sc, ay = (v1[i0 * 3 + 1] - cy0) / sc,
              az = (v1[i0 * 3 + 2] - cz0) / sc;
        float bx = (v1[i1 * 3 + 0] - cx0) / sc, by = (v1[i1 * 3 + 1] - cy0) / sc,
              bz = (v1[i1 * 3 + 2] - cz0) / sc;
        float cx = (v1[i2 * 3 + 0] - cx0) / sc, cy = (v1[i2 * 3 + 1] - cy0) / sc,
              cz = (v1[i2 * 3 + 2] - cz0) / sc;
        float aby = by - ay, abz = bz - az;
        float acy = cy - ay, acz = cz - az;
        float det = aby * (-acz) + abz * acy;
        float dd = (fabsf(det) < 1e-12f) ? 1e-12f : det;
        float inv = 1.0f / dd;  // IEEE — parity test must stay bit-exact
        float* r = tri + (size_t)f * 12;
        r[0] = ax; r[1] = ay; r[2] = az;
        r[3] = bx; r[4] = by; r[5] = bz;
        r[6] = cx; r[7] = cy; r[8] = cz;
        r[9] = inv; r[10] = det; r[11] = 0.0f;
    }

    // mark + compact the grid nodes actually read by trilinear (hull-0 points)
    for (int i = threadIdx.x; i < V; i += blockDim.x) {
        float px = (verts[i * 3 + 0] - cx0) / sc;
        float py = (verts[i * 3 + 1] - cy0) / sc;
        float pz = (verts[i * 3 + 2] - cz0) / sc;
        int x0, y0, z0; float wx, wy, wz;
        cell_of(px, py, pz, x0, y0, z0, wx, wy, wz);
        for (int dz = 0; dz < 2; ++dz) {
            int zi = z0 + dz;
            if (zi < 0 || zi > 31) continue;
            for (int dy = 0; dy < 2; ++dy) {
                int yi = y0 + dy;
                if (yi < 0 || yi > 31) continue;
                for (int dx = 0; dx < 2; ++dx) {
                    int xi = x0 + dx;
                    if (xi < 0 || xi > 31) continue;
                    int node = zi * 1024 + yi * 32 + xi;
                    if (atomicExch(&flags[node], 1) == 0) {
                        int p = atomicAdd(cnt, 1);
                        list[p] = node;
                    }
                }
            }
        }
    }
}

// ---- main: one wave per (active node, 64-triangle chunk), persistent grid ----
__global__ void __launch_bounds__(256) k_main(const float* __restrict__ tri,
                                              const int* __restrict__ list,
                                              const int* __restrict__ cnt,
                                              unsigned int* __restrict__ d2b,
                                              int* __restrict__ hits,
                                              int F, int nch,
                                              unsigned long long magic) {
    const int wave = threadIdx.x >> 6, lane = threadIdx.x & 63;
    const int wid = blockIdx.x * 4 + wave;
    const int nw = gridDim.x * 4;
    const int n = cnt[0];
    const int total = n * nch;
    for (int w = wid; w < total; w += nw) {
        const int q = (int)(((unsigned long long)(unsigned int)w * magic) >> 40);
        const int ck = w - q * nch;
        const int node = list[q];
        const int xi = node & 31, yi = (node >> 5) & 31, zi = node >> 10;
        float px, py, pz;
        {
#pragma clang fp contract(off)
            px = (float)((double)xi * (2.0 / 31.0) - 1.0);
            py = (float)((double)yi * (2.0 / 31.0) - 1.0);
            pz = (float)((double)zi * (2.0 / 31.0) - 1.0);
        }
        float mind2 = 1e30f;
        int h = 0;
        const int f = ck * 64 + lane;
        if (f < F) {
            const float* r = tri + (size_t)f * 12;
            float ax = r[0], ay = r[1], az = r[2];
            float bx = r[3], by = r[4], bz = r[5];
            float cx = r[6], cy = r[7], cz = r[8];
            float inv = r[9], det = r[10];
            float abx = bx - ax, aby = by - ay, abz = bz - az;
            float acx = cx - ax, acy = cy - ay, acz = cz - az;
            float apx = px - ax, apy = py - ay, apz = pz - az;
            // ---- distance path: contraction + fast rcp (continuous at all branch bounds)
            {
#pragma clang fp contract(fast)
                float d1 = abx * apx + aby * apy + abz * apz;
                float d2 = acx * apx + acy * apy + acz * apz;
                float bpx = px - bx, bpy = py - by, bpz = pz - bz;
                float d3 = abx * bpx + aby * bpy + abz * bpz;
                float d4 = acx * bpx + acy * bpy + acz * bpz;
                float cpx = px - cx, cpy = py - cy, cpz = pz - cz;
                float d5 = abx * cpx + aby * cpy + abz * cpz;
                float d6 = acx * cpx + acy * cpy + acz * cpz;
                float vc = d1 * d4 - d3 * d2;
                float vb = d5 * d2 - d1 * d6;
                float va = d3 * d6 - d5 * d4;
                float denom = va + vb + vc;
                float rd = rguard(denom);
                float v_in = vb * rd, w_in = vc * rd;
                float rx = ax + abx * v_in + acx * w_in;
                float ry = ay + aby * v_in + acy * w_in;
                float rz = az + abz * v_in + acz * w_in;
                if (va <= 0.0f && (d4 - d3) >= 0.0f && (d5 - d6) >= 0.0f) {
                    float w = (d4 - d3) * rguard((d4 - d3) + (d5 - d6));
                    rx = bx + (cx - bx) * w; ry = by + (cy - by) * w; rz = bz + (cz - bz) * w;
                }
                if (vb <= 0.0f && d2 >= 0.0f && d6 <= 0.0f) {
                    float w = d2 * rguard(d2 - d6);
                    rx = ax + acx * w; ry = ay + acy * w; rz = az + acz * w;
                }
                if (vc <= 0.0f && d1 >= 0.0f && d3 <= 0.0f) {
                    float w = d1 * rguard(d1 - d3);
                    rx = ax + abx * w; ry = ay + aby * w; rz = az + abz * w;
                }
                if (d6 >= 0.0f && d5 <= d6) { rx = cx; ry = cy; rz = cz; }
                if (d3 >= 0.0f && d4 <= d3) { rx = bx; ry = by; rz = bz; }
                if (d1 <= 0.0f && d2 <= 0.0f) { rx = ax; ry = ay; rz = az; }
                float ddx = px - rx, ddy = py - ry, ddz = pz - rz;
                mind2 = ddx * ddx + ddy * ddy + ddz * ddz;
            }
            // ---- parity path: bit-exact (discontinuous: a flip costs ~0.1 on the loss)
            {
#pragma clang fp contract(off)
                float u = (apy * (-acz) + apz * acy) * inv;
                float qx = apy * abz - apz * aby;
                float qy = apz * abx - apx * abz;
                float qz = apx * aby - apy * abx;
                float v = qx * inv;
                float tt = (acx * qx + acy * qy + acz * qz) * inv;
                h = (fabsf(det) > 1e-9f && u >= 0.0f && u <= 1.0f && v >= 0.0f &&
                     (u + v) <= 1.0f && tt > 0.0f) ? 1 : 0;
            }
        }
        for (int off = 32; off >= 1; off >>= 1) {
            mind2 = fminf(mind2, __shfl_xor(mind2, off));
            h += __shfl_xor(h, off);
        }
        if (lane == 0) {
            atomicMin(d2b + node, __float_as_uint(mind2));
            atomicAdd(hits + node, h);
        }
    }
}

// ---- trilinear sample at hull-0 vertices + reduce; phi built on the fly ----
__global__ void k_sum(const float* __restrict__ verts, const float* __restrict__ par,
                      const unsigned int* __restrict__ d2b, const int* __restrict__ hits,
                      float* __restrict__ out, int V) {
#pragma clang fp contract(off)
    int t = threadIdx.x;
    float val = 0.0f;
    float cx = par[0], cy = par[1], cz = par[2], sc = par[3];
    for (int i = t; i < V; i += 1024) {
        float px = (verts[i * 3 + 0] - cx) / sc;
        float py = (verts[i * 3 + 1] - cy) / sc;
        float pz = (verts[i * 3 + 2] - cz) / sc;
        int x0, y0, z0; float wx, wy, wz;
        cell_of(px, py, pz, x0, y0, z0, wx, wy, wz);
        auto corner = [&](int zi, int yi, int xi, float w) -> float {
#pragma clang fp contract(off)
            bool valid = (zi >= 0) && (zi <= 31) && (yi >= 0) && (yi <= 31) &&
                         (xi >= 0) && (xi <= 31);
            int zc = min(max(zi, 0), 31);
            int yc = min(max(yi, 0), 31);
            int xc = min(max(xi, 0), 31);
            int idx = zc * 1024 + yc * 32 + xc;
            float vv = (hits[idx] & 1) ? sqrtf(fmaxf(__uint_as_float(d2b[idx]), 0.0f))
                                       : 0.0f;
            return valid ? vv * w : 0.0f;
        };
        val += corner(z0, y0, x0, (1.0f - wz) * (1.0f - wy) * (1.0f - wx))
             + corner(z0, y0, x0 + 1, (1.0f - wz) * (1.0f - wy) * wx)
             + corner(z0, y0 + 1, x0, (1.0f - wz) * wy * (1.0f - wx))
             + corner(z0, y0 + 1, x0 + 1, (1.0f - wz) * wy * wx)
             + corner(z0 + 1, y0, x0, wz * (1.0f - wy) * (1.0f - wx))
             + corner(z0 + 1, y0, x0 + 1, wz * (1.0f - wy) * wx)
             + corner(z0 + 1, y0 + 1, x0, wz * wy * (1.0f - wx))
             + corner(z0 + 1, y0 + 1, x0 + 1, wz * wy * wx);
    }
    __shared__ float sm[1024];
    sm[t] = val;
    __syncthreads();
    for (int s = 512; s >= 1; s >>= 1) {
        if (t < s) sm[t] += sm[t + s];
        __syncthreads();
    }
    if (t == 0) out[0] = sm[0] * 0.25f;  // / H^2, H=2
}

extern "C" void kernel_launch(void* const* d_in, const int* in_sizes, int n_in,
                              void* d_out, int out_size, void* d_ws, size_t ws_size,
                              hipStream_t stream) {
    const float* verts = (const float*)d_in[0];
    const int* faces = (const int*)d_in[1];
    float* out = (float*)d_out;
    float* ws = (float*)d_ws;

    int V = in_sizes[0] / 6;  // 2 hulls x 3 comps
    int F = in_sizes[1] / 3;

    float* par = ws;                                   // 4 floats
    float* tri = ws + 16;                              // 12*F floats
    unsigned int* d2b = (unsigned int*)(tri + 12 * (size_t)F);
    int* hits = (int*)(d2b + NNODE);
    int* flags = hits + NNODE;
    int* cnt = flags + NNODE;
    int* list = cnt + 1;                               // up to 8*V entries

    int nch = (F + 63) / 64;
    unsigned long long magic = ((1ULL << 40) + (unsigned long long)nch - 1) / (unsigned long long)nch;

    k_init<<<64, 256, 0, stream>>>((uint4*)d2b, (uint4*)hits, cnt);
    k_setup<<<1, 256, 0, stream>>>(verts, faces, par, tri, flags, cnt, list, V, F);
    k_main<<<2048, 256, 0, stream>>>(tri, list, cnt, d2b, hits, F, nch, magic);
    k_sum<<<1, 1024, 0, stream>>>(verts, par, d2b, hits, out, V);
}